// Round 6
// baseline (283.091 us; speedup 1.0000x reference)
//
#include <hip/hip_runtime.h>
#include <hip/hip_bf16.h>
#include <math.h>

typedef __bf16 bf16;
typedef __bf16 bf16x8 __attribute__((ext_vector_type(8)));
typedef float f32x4 __attribute__((ext_vector_type(4)));

#define SEQ  2048
#define EMB  1024
#define NH   16
#define HD   64
#define MTOT 4096  // B*S

__device__ __forceinline__ void gl_lds16(const void* g, void* l) {
  __builtin_amdgcn_global_load_lds(
      (const __attribute__((address_space(1))) void*)g,
      (__attribute__((address_space(3))) void*)l, 16, 0, 0);
}

__device__ __forceinline__ f32x4 mfma16(bf16x8 a, bf16x8 b, f32x4 c) {
  return __builtin_amdgcn_mfma_f32_16x16x32_bf16(a, b, c, 0, 0, 0);
}

// f32 -> bf16 conversion, 8 elems/thread
__global__ __launch_bounds__(256) void cvt8_kernel(
    const float* __restrict__ s, bf16* __restrict__ d, int n) {
  int i = (blockIdx.x * 256 + threadIdx.x) * 8;
  if (i >= n) return;
  float4 a = *(const float4*)(s + i);
  float4 b = *(const float4*)(s + i + 4);
  bf16x8 o;
  o[0] = (bf16)a.x; o[1] = (bf16)a.y; o[2] = (bf16)a.z; o[3] = (bf16)a.w;
  o[4] = (bf16)b.x; o[5] = (bf16)b.y; o[6] = (bf16)b.z; o[7] = (bf16)b.w;
  *(bf16x8*)(d + i) = o;
}

// 4 weight matrices (EMB*EMB each) -> contiguous bf16 dst, grid.y selects source
__global__ __launch_bounds__(256) void cvtw_kernel(
    const float* __restrict__ w0, const float* __restrict__ w1,
    const float* __restrict__ w2, const float* __restrict__ w3,
    bf16* __restrict__ d) {
  const float* src = (blockIdx.y == 0) ? w0 : (blockIdx.y == 1) ? w1
                   : (blockIdx.y == 2) ? w2 : w3;
  int i = (blockIdx.x * 256 + threadIdx.x) * 8;
  float4 a = *(const float4*)(src + i);
  float4 b = *(const float4*)(src + i + 4);
  bf16x8 o;
  o[0] = (bf16)a.x; o[1] = (bf16)a.y; o[2] = (bf16)a.z; o[3] = (bf16)a.w;
  o[4] = (bf16)b.x; o[5] = (bf16)b.y; o[6] = (bf16)b.z; o[7] = (bf16)b.w;
  *(bf16x8*)(d + (size_t)blockIdx.y * (EMB * EMB) + i) = o;
}

// log2(10000)/32
#define ROPE_C 0.41524101186092026f

// MODE 0: z = blockIdx.z selects {q,k,v}; RoPE on q,k; q,k -> [bh][s][d], v -> [bh][d][s]
//         epilogue round-trips C tile through LDS for fully-coalesced wide stores.
// MODE 1: plain float out[m][n] store (out projection)
template <int MODE>
__global__ __launch_bounds__(256) void gemm_kernel(
    const bf16* __restrict__ X,
    const bf16* __restrict__ W0, const bf16* __restrict__ W1, const bf16* __restrict__ W2,
    const float* __restrict__ B0, const float* __restrict__ B1, const float* __restrict__ B2,
    bf16* __restrict__ Oq, bf16* __restrict__ Ok, bf16* __restrict__ Ovt,
    float* __restrict__ Oplain)
{
  const int K = EMB;
  const int tid  = threadIdx.x;
  const int lane = tid & 63;
  const int w    = tid >> 6;       // wave 0..3
  const int wm   = w >> 1, wn = w & 1;
  const int tile_n = blockIdx.x * 128;
  const int tile_m = blockIdx.y * 128;
  const int z = (MODE == 0) ? blockIdx.z : 0;
  const bf16*  Wsel = (MODE == 0) ? (z == 0 ? W0 : (z == 1 ? W1 : W2)) : W0;
  const float* Bsel = (MODE == 0) ? (z == 0 ? B0 : (z == 1 ? B1 : B2)) : B0;

  // MODE 0: 33792 B (C-tile transpose buffer, overlays As/Bs). MODE 1: 16 KB.
  constexpr int SMEM_BYTES = (MODE == 0) ? (128 * 132 * 2) : 16384;
  __shared__ __align__(16) unsigned char smem[SMEM_BYTES];
  bf16* As = (bf16*)smem;            // 128*32 = 8 KB
  bf16* Bs = (bf16*)(smem + 8192);   // 128*32 = 8 KB

  f32x4 acc[4][4];
#pragma unroll
  for (int i = 0; i < 4; i++)
#pragma unroll
    for (int j = 0; j < 4; j++) acc[i][j] = f32x4{0.f, 0.f, 0.f, 0.f};

  const int quad = lane >> 4;
  const int l15  = lane & 15;
  const int srow = lane >> 2;   // 0..15 within a 16-row staging issue
  const int scl  = lane & 3;    // LDS chunk position within 64B row

  for (int k0 = 0; k0 < K; k0 += 32) {
#pragma unroll
    for (int i = 0; i < 2; i++) {
      int r = i * 64 + w * 16 + srow;           // tile-local row 0..127
      int c = scl ^ ((r >> 1) & 3);             // data chunk for this LDS slot
      gl_lds16(X    + (size_t)(tile_m + r) * K + k0 + c * 8, As + (i * 64 + w * 16) * 32);
      gl_lds16(Wsel + (size_t)(tile_n + r) * K + k0 + c * 8, Bs + (i * 64 + w * 16) * 32);
    }
    __syncthreads();

    bf16x8 af[4], bfr[4];
#pragma unroll
    for (int mt = 0; mt < 4; mt++) {
      int ml = wm * 64 + mt * 16 + l15;
      af[mt] = *(const bf16x8*)(As + ml * 32 + (quad ^ ((ml >> 1) & 3)) * 8);
    }
#pragma unroll
    for (int nt = 0; nt < 4; nt++) {
      int nl = wn * 64 + nt * 16 + l15;
      bfr[nt] = *(const bf16x8*)(Bs + nl * 32 + (quad ^ ((nl >> 1) & 3)) * 8);
    }
#pragma unroll
    for (int mt = 0; mt < 4; mt++)
#pragma unroll
      for (int nt = 0; nt < 4; nt++)
        acc[mt][nt] = mfma16(af[mt], bfr[nt], acc[mt][nt]);
    __syncthreads();
  }

  // ---- epilogue ----
  if constexpr (MODE == 0) {
    bf16* CS = (bf16*)smem;  // 128 rows x 132 stride (As/Bs dead after last sync)
    const int b = tile_m >> 11;
    const int s0 = tile_m & (SEQ - 1);

    if (z < 2) {
      // bias + RoPE in registers, stage CS[m][n]
#pragma unroll
      for (int nt = 0; nt < 4; nt++) {
        const int nl = wn * 64 + nt * 16 + l15;
        const int n = tile_n + nl;
        const float bias = Bsel[n];
        const int j = n & 31;
        const float invf = exp2f(-(float)j * ROPE_C);
#pragma unroll
        for (int mt = 0; mt < 4; mt++) {
#pragma unroll
          for (int r = 0; r < 4; r++) {
            const int ml = wm * 64 + mt * 16 + quad * 4 + r;
            float a = acc[mt][nt][r] + bias;
            float p = __shfl_xor(a, 1, 64);  // partner at d^1 (incl. its bias)
            float th = (float)((s0 + ml) & (SEQ - 1)) * invf;
            float sn, cs;
            __sincosf(th, &sn, &cs);  // inline v_sin/v_cos: NO libcall, NO scratch spill
            float res = (n & 1) ? fmaf(p, sn, a * cs) : fmaf(-p, sn, a * cs);
            CS[ml * 132 + nl] = (bf16)res;
          }
        }
      }
      __syncthreads();
      // coalesced store: 256 rows (2 heads x 128 s), 128 B each
      bf16* Odst = (z == 0) ? Oq : Ok;
#pragma unroll
      for (int g = 0; g < 8; g++) {
        int unit = g * 256 + tid;
        int chunk = unit & 7;          // 16B chunk within row
        int row = unit >> 3;           // 0..255
        int hl = row >> 7, sl = row & 127;
        bf16x8 v = *(const bf16x8*)(CS + sl * 132 + hl * 64 + chunk * 8);
        int hg = (tile_n >> 6) + hl;
        size_t o = ((size_t)(b * NH + hg) * SEQ + s0 + sl) * HD + chunk * 8;
        *(bf16x8*)(Odst + o) = v;
      }
    } else {
      // V^T: stage CS[n][m] (r-contiguous writes), rows = d, cols = s
#pragma unroll
      for (int nt = 0; nt < 4; nt++) {
        const int nl = wn * 64 + nt * 16 + l15;
        const float bias = Bsel[tile_n + nl];
#pragma unroll
        for (int mt = 0; mt < 4; mt++) {
          const int mb = wm * 64 + mt * 16 + quad * 4;
#pragma unroll
          for (int r = 0; r < 4; r++)
            CS[nl * 132 + mb + r] = (bf16)(acc[mt][nt][r] + bias);
        }
      }
      __syncthreads();
      // coalesced store: 128 rows (d), 256 B each
#pragma unroll
      for (int g = 0; g < 8; g++) {
        int unit = g * 256 + tid;
        int chunk = unit & 15;         // 16B chunk within row
        int row = unit >> 4;           // 0..127 (n_local)
        bf16x8 v = *(const bf16x8*)(CS + row * 132 + chunk * 8);
        int nglob = tile_n + row;
        int d = nglob & 63, hg = nglob >> 6;
        size_t o = ((size_t)(b * NH + hg) * HD + d) * SEQ + s0 + chunk * 8;
        *(bf16x8*)(Ovt + o) = v;
      }
    }
  } else {
    // out projection: f32 stores, 64B contiguous per quad-row
#pragma unroll
    for (int nt = 0; nt < 4; nt++) {
      const int n = tile_n + wn * 64 + nt * 16 + l15;
      const float bias = Bsel[n];
#pragma unroll
      for (int mt = 0; mt < 4; mt++) {
#pragma unroll
        for (int r = 0; r < 4; r++) {
          const int m = tile_m + wm * 64 + mt * 16 + quad * 4 + r;
          Oplain[(size_t)m * EMB + n] = acc[mt][nt][r] + bias;
        }
      }
    }
  }
}

// Flash attention v3: K-PARTITIONED waves. Each of 4 waves owns a 32-kcol
// slice of the 128-k tile: QK reads only its K slice (4 b128/iter vs 16),
// PV reads only its V slice (4 vs 16); Q (64 rows) preloaded in registers.
// O is accumulated k-partial per wave and reduced through LDS at the end.
// Fixed-max softmax (|s/8| < ~4 << 88 -> exp2 cannot overflow, shift-invariant
// softmax makes m=0 exact); row sums deferred: per-lane partials + one
// butterfly + cross-wave LDS sum at the end. LDS = 48 KB.
__global__ __launch_bounds__(256) void flash_kernel(
    const bf16* __restrict__ Q,   // [bh][s][d]
    const bf16* __restrict__ Kk,  // [bh][s][d]
    const bf16* __restrict__ Vt,  // [bh][d][s]
    bf16* __restrict__ O)         // [b*S + s][h*64 + d]
{
  const int bh = blockIdx.y;
  const int qt = blockIdx.x;
  const int tid = threadIdx.x, lane = tid & 63, w = tid >> 6;
  const int quad = lane >> 4, l15 = lane & 15;

  __shared__ __align__(16) unsigned char smem[49152];
  bf16* Ks = (bf16*)smem;             // 16 KB [128 krow][64 d], chunk^(row&7)
  bf16* Vs = (bf16*)(smem + 16384);   // 16 KB [64 d][128 s], chunk^(d&15)
  bf16* Ps = (bf16*)(smem + 32768);   // 16 KB [wave][64 q][32 k], chunk^((q>>2)&3)

  const bf16* qbase = Q  + (size_t)bh * SEQ * HD;
  const bf16* kbase = Kk + (size_t)bh * SEQ * HD;
  const bf16* vbase = Vt + (size_t)bh * HD * SEQ;

  // preload entire 64-row Q tile: qf[m][t] -> rows m*16+l15, k = t*32+quad*8
  bf16x8 qf[4][2];
#pragma unroll
  for (int m = 0; m < 4; m++)
#pragma unroll
    for (int t = 0; t < 2; t++)
      qf[m][t] = *(const bf16x8*)(qbase + (size_t)(qt * 64 + m * 16 + l15) * HD
                                  + t * 32 + quad * 8);

  float lsum[4][4];
  f32x4 oacc[4][4];
#pragma unroll
  for (int m = 0; m < 4; m++)
#pragma unroll
    for (int i = 0; i < 4; i++) { lsum[m][i] = 0.f; oacc[m][i] = f32x4{0.f, 0.f, 0.f, 0.f}; }

  const float SCL = 0.1803368801111244f;  // log2(e)/8

  for (int kt = 0; kt < SEQ / 128; kt++) {
    // stage K tile (16KB) and V^T tile (16KB)
#pragma unroll
    for (int i = 0; i < 4; i++) {
      int r = w * 32 + i * 8 + (lane >> 3);             // K row 0..127
      int c = (lane & 7) ^ (r & 7);
      gl_lds16(kbase + (size_t)(kt * 128 + r) * HD + c * 8, Ks + (w * 32 + i * 8) * 64);
      int dv = w * 16 + i * 4 + (lane >> 4);            // V^T row (d) 0..63
      int cv = (lane & 15) ^ (dv & 15);
      gl_lds16(vbase + (size_t)dv * SEQ + kt * 128 + cv * 8, Vs + (w * 16 + i * 4) * 128);
    }
    __syncthreads();

    // QK over this wave's 32-kcol window; K frags loaded once, reused by 4 m-tiles
    bf16x8 kfr[2][2];
#pragma unroll
    for (int nt = 0; nt < 2; nt++) {
      int krow = w * 32 + nt * 16 + l15;
#pragma unroll
      for (int t = 0; t < 2; t++)
        kfr[nt][t] = *(const bf16x8*)(Ks + krow * 64 + (((t * 4 + quad) ^ (l15 & 7)) & 7) * 8);
    }
#pragma unroll
    for (int m = 0; m < 4; m++) {
#pragma unroll
      for (int nt = 0; nt < 2; nt++) {
        f32x4 s = f32x4{0.f, 0.f, 0.f, 0.f};
        s = mfma16(qf[m][0], kfr[nt][0], s);
        s = mfma16(qf[m][1], kfr[nt][1], s);
#pragma unroll
        for (int r = 0; r < 4; r++) {
          float p = __builtin_amdgcn_exp2f(s[r] * SCL);
          lsum[m][r] += p;
          int q = m * 16 + quad * 4 + r;                 // (q>>2)&3 == quad
          int kcol = nt * 16 + l15;
          int ch = ((kcol >> 3) ^ quad) & 3;
          Ps[w * 2048 + q * 32 + ch * 8 + (kcol & 7)] = (bf16)p;
        }
      }
    }

    // PV over own window: V frags loaded once, reused by 4 m-tiles
    bf16x8 vfr[4];
#pragma unroll
    for (int dt = 0; dt < 4; dt++) {
      int d = dt * 16 + l15;
      vfr[dt] = *(const bf16x8*)(Vs + d * 128 + (((w * 4 + quad) ^ l15) & 15) * 8);
    }
#pragma unroll
    for (int m = 0; m < 4; m++) {
      int q = m * 16 + l15;                              // (q>>2)&3 == l15>>2
      bf16x8 pf = *(const bf16x8*)(Ps + w * 2048 + q * 32 + ((quad ^ (l15 >> 2)) & 3) * 8);
#pragma unroll
      for (int dt = 0; dt < 4; dt++)
        oacc[m][dt] = mfma16(pf, vfr[dt], oacc[m][dt]);
    }
    __syncthreads();
  }

  // ---- cross-wave reduction ----
  float* Obuf  = (float*)smem;            // 64 x 68-stride f32 (17408 B, over Ks+Vs)
  float* LsumB = (float*)(smem + 32768);  // [4][64] f32 (over Ps)

  // row-sum butterfly over l15 bits (rows live per-quad)
#pragma unroll
  for (int m = 0; m < 4; m++)
#pragma unroll
    for (int r = 0; r < 4; r++) {
      float s = lsum[m][r];
      s += __shfl_xor(s, 1, 64);
      s += __shfl_xor(s, 2, 64);
      s += __shfl_xor(s, 4, 64);
      s += __shfl_xor(s, 8, 64);
      lsum[m][r] = s;
    }
  if (l15 == 0) {
#pragma unroll
    for (int m = 0; m < 4; m++)
#pragma unroll
      for (int r = 0; r < 4; r++)
        LsumB[w * 64 + m * 16 + quad * 4 + r] = lsum[m][r];
  }
  if (w == 0) {
#pragma unroll
    for (int m = 0; m < 4; m++)
#pragma unroll
      for (int dt = 0; dt < 4; dt++)
#pragma unroll
        for (int r = 0; r < 4; r++)
          Obuf[(m * 16 + quad * 4 + r) * 68 + dt * 16 + l15] = oacc[m][dt][r];
  }
  __syncthreads();
#pragma unroll
  for (int v = 1; v < 4; v++) {
    if (w == v) {
#pragma unroll
      for (int m = 0; m < 4; m++)
#pragma unroll
        for (int dt = 0; dt < 4; dt++)
#pragma unroll
          for (int r = 0; r < 4; r++)
            Obuf[(m * 16 + quad * 4 + r) * 68 + dt * 16 + l15] += oacc[m][dt][r];
    }
    __syncthreads();
  }

  // final: each wave stores 16 rows, fully coalesced 16B stores
  const int b = bh >> 4, h = bh & 15;
  {
    int row = w * 16 + l15;
    float lt = LsumB[row] + LsumB[64 + row] + LsumB[128 + row] + LsumB[192 + row];
    float inv = __builtin_amdgcn_rcpf(lt);
    f32x4 v0 = *(const f32x4*)(Obuf + row * 68 + quad * 16);
    f32x4 v1 = *(const f32x4*)(Obuf + row * 68 + quad * 16 + 4);
    f32x4 v2 = *(const f32x4*)(Obuf + row * 68 + quad * 16 + 8);
    f32x4 v3 = *(const f32x4*)(Obuf + row * 68 + quad * 16 + 12);
    bf16x8 o0, o1;
#pragma unroll
    for (int i = 0; i < 4; i++) {
      o0[i]     = (bf16)(v0[i] * inv);
      o0[i + 4] = (bf16)(v1[i] * inv);
      o1[i]     = (bf16)(v2[i] * inv);
      o1[i + 4] = (bf16)(v3[i] * inv);
    }
    size_t gb = ((size_t)(b * SEQ + qt * 64 + row)) * EMB + h * HD + quad * 16;
    *(bf16x8*)(O + gb) = o0;
    *(bf16x8*)(O + gb + 8) = o1;
  }
}

extern "C" void kernel_launch(void* const* d_in, const int* in_sizes, int n_in,
                              void* d_out, int out_size, void* d_ws, size_t ws_size,
                              hipStream_t stream) {
  const float* x  = (const float*)d_in[0];
  const float* Wq = (const float*)d_in[1];
  const float* bq = (const float*)d_in[2];
  const float* Wk = (const float*)d_in[3];
  const float* bk = (const float*)d_in[4];
  const float* Wv = (const float*)d_in[5];
  const float* bv = (const float*)d_in[6];
  const float* Wo = (const float*)d_in[7];
  const float* bo = (const float*)d_in[8];

  const size_t XN = (size_t)MTOT * EMB;  // 4,194,304
  const size_t WN = (size_t)EMB * EMB;   // 1,048,576

  bf16* xb = (bf16*)d_ws;
  bf16* wq = xb + XN;                    // wq,wk,wv,wo contiguous (cvtw uses this)
  bf16* wk = wq + WN;
  bf16* wv = wk + WN;
  bf16* wo = wv + WN;
  bf16* q  = wo + WN;
  bf16* k  = q + XN;
  bf16* vt = k + XN;
  bf16* at = vt + XN;
  float* out = (float*)d_out;

  dim3 blk(256);
  cvt8_kernel<<<dim3((int)(XN / (256 * 8))), blk, 0, stream>>>(x, xb, (int)XN);
  cvtw_kernel<<<dim3((int)(WN / (256 * 8)), 4), blk, 0, stream>>>(Wq, Wk, Wv, Wo, wq);

  gemm_kernel<0><<<dim3(8, 32, 3), blk, 0, stream>>>(
      xb, wq, wk, wv, bq, bk, bv, q, k, vt, nullptr);
  flash_kernel<<<dim3(32, 32), blk, 0, stream>>>(q, k, vt, at);
  gemm_kernel<1><<<dim3(8, 32, 1), blk, 0, stream>>>(
      at, wo, nullptr, nullptr, bo, nullptr, nullptr, nullptr, nullptr, nullptr, out);
}

// Round 7
// 220.377 us; speedup vs baseline: 1.2846x; 1.2846x over previous
//
#include <hip/hip_runtime.h>
#include <hip/hip_bf16.h>
#include <math.h>

typedef __bf16 bf16;
typedef __bf16 bf16x8 __attribute__((ext_vector_type(8)));
typedef float f32x4 __attribute__((ext_vector_type(4)));

#define SEQ  2048
#define EMB  1024
#define NH   16
#define HD   64
#define MTOT 4096  // B*S

__device__ __forceinline__ void gl_lds16(const void* g, void* l) {
  __builtin_amdgcn_global_load_lds(
      (const __attribute__((address_space(1))) void*)g,
      (__attribute__((address_space(3))) void*)l, 16, 0, 0);
}

__device__ __forceinline__ f32x4 mfma16(bf16x8 a, bf16x8 b, f32x4 c) {
  return __builtin_amdgcn_mfma_f32_16x16x32_bf16(a, b, c, 0, 0, 0);
}

// f32 -> bf16 conversion, 8 elems/thread
__global__ __launch_bounds__(256) void cvt8_kernel(
    const float* __restrict__ s, bf16* __restrict__ d, int n) {
  int i = (blockIdx.x * 256 + threadIdx.x) * 8;
  if (i >= n) return;
  float4 a = *(const float4*)(s + i);
  float4 b = *(const float4*)(s + i + 4);
  bf16x8 o;
  o[0] = (bf16)a.x; o[1] = (bf16)a.y; o[2] = (bf16)a.z; o[3] = (bf16)a.w;
  o[4] = (bf16)b.x; o[5] = (bf16)b.y; o[6] = (bf16)b.z; o[7] = (bf16)b.w;
  *(bf16x8*)(d + i) = o;
}

// 4 weight matrices (EMB*EMB each) -> contiguous bf16 dst, grid.y selects source
__global__ __launch_bounds__(256) void cvtw_kernel(
    const float* __restrict__ w0, const float* __restrict__ w1,
    const float* __restrict__ w2, const float* __restrict__ w3,
    bf16* __restrict__ d) {
  const float* src = (blockIdx.y == 0) ? w0 : (blockIdx.y == 1) ? w1
                   : (blockIdx.y == 2) ? w2 : w3;
  int i = (blockIdx.x * 256 + threadIdx.x) * 8;
  float4 a = *(const float4*)(src + i);
  float4 b = *(const float4*)(src + i + 4);
  bf16x8 o;
  o[0] = (bf16)a.x; o[1] = (bf16)a.y; o[2] = (bf16)a.z; o[3] = (bf16)a.w;
  o[4] = (bf16)b.x; o[5] = (bf16)b.y; o[6] = (bf16)b.z; o[7] = (bf16)b.w;
  *(bf16x8*)(d + (size_t)blockIdx.y * (EMB * EMB) + i) = o;
}

// log2(10000)/32
#define ROPE_C 0.41524101186092026f

// MODE 0: z = blockIdx.z selects {q,k,v}; RoPE on q,k; q,k -> [bh][s][d], v -> [bh][d][s]
//         epilogue round-trips C tile through LDS for fully-coalesced wide stores.
// MODE 1: plain float out[m][n] store (out projection)
template <int MODE>
__global__ __launch_bounds__(256) void gemm_kernel(
    const bf16* __restrict__ X,
    const bf16* __restrict__ W0, const bf16* __restrict__ W1, const bf16* __restrict__ W2,
    const float* __restrict__ B0, const float* __restrict__ B1, const float* __restrict__ B2,
    bf16* __restrict__ Oq, bf16* __restrict__ Ok, bf16* __restrict__ Ovt,
    float* __restrict__ Oplain)
{
  const int K = EMB;
  const int tid  = threadIdx.x;
  const int lane = tid & 63;
  const int w    = tid >> 6;       // wave 0..3
  const int wm   = w >> 1, wn = w & 1;
  const int tile_n = blockIdx.x * 128;
  const int tile_m = blockIdx.y * 128;
  const int z = (MODE == 0) ? blockIdx.z : 0;
  const bf16*  Wsel = (MODE == 0) ? (z == 0 ? W0 : (z == 1 ? W1 : W2)) : W0;
  const float* Bsel = (MODE == 0) ? (z == 0 ? B0 : (z == 1 ? B1 : B2)) : B0;

  // MODE 0: 33792 B (C-tile transpose buffer, overlays As/Bs). MODE 1: 16 KB.
  constexpr int SMEM_BYTES = (MODE == 0) ? (128 * 132 * 2) : 16384;
  __shared__ __align__(16) unsigned char smem[SMEM_BYTES];
  bf16* As = (bf16*)smem;            // 128*32 = 8 KB
  bf16* Bs = (bf16*)(smem + 8192);   // 128*32 = 8 KB

  f32x4 acc[4][4];
#pragma unroll
  for (int i = 0; i < 4; i++)
#pragma unroll
    for (int j = 0; j < 4; j++) acc[i][j] = f32x4{0.f, 0.f, 0.f, 0.f};

  const int quad = lane >> 4;
  const int l15  = lane & 15;
  const int srow = lane >> 2;   // 0..15 within a 16-row staging issue
  const int scl  = lane & 3;    // LDS chunk position within 64B row

  for (int k0 = 0; k0 < K; k0 += 32) {
#pragma unroll
    for (int i = 0; i < 2; i++) {
      int r = i * 64 + w * 16 + srow;           // tile-local row 0..127
      int c = scl ^ ((r >> 1) & 3);             // data chunk for this LDS slot
      gl_lds16(X    + (size_t)(tile_m + r) * K + k0 + c * 8, As + (i * 64 + w * 16) * 32);
      gl_lds16(Wsel + (size_t)(tile_n + r) * K + k0 + c * 8, Bs + (i * 64 + w * 16) * 32);
    }
    __syncthreads();

    bf16x8 af[4], bfr[4];
#pragma unroll
    for (int mt = 0; mt < 4; mt++) {
      int ml = wm * 64 + mt * 16 + l15;
      af[mt] = *(const bf16x8*)(As + ml * 32 + (quad ^ ((ml >> 1) & 3)) * 8);
    }
#pragma unroll
    for (int nt = 0; nt < 4; nt++) {
      int nl = wn * 64 + nt * 16 + l15;
      bfr[nt] = *(const bf16x8*)(Bs + nl * 32 + (quad ^ ((nl >> 1) & 3)) * 8);
    }
#pragma unroll
    for (int mt = 0; mt < 4; mt++)
#pragma unroll
      for (int nt = 0; nt < 4; nt++)
        acc[mt][nt] = mfma16(af[mt], bfr[nt], acc[mt][nt]);
    __syncthreads();
  }

  // ---- epilogue ----
  if constexpr (MODE == 0) {
    bf16* CS = (bf16*)smem;  // 128 rows x 132 stride (As/Bs dead after last sync)
    const int b = tile_m >> 11;
    const int s0 = tile_m & (SEQ - 1);

    if (z < 2) {
      // bias + RoPE in registers, stage CS[m][n]
#pragma unroll
      for (int nt = 0; nt < 4; nt++) {
        const int nl = wn * 64 + nt * 16 + l15;
        const int n = tile_n + nl;
        const float bias = Bsel[n];
        const int j = n & 31;
        const float invf = exp2f(-(float)j * ROPE_C);
#pragma unroll
        for (int mt = 0; mt < 4; mt++) {
#pragma unroll
          for (int r = 0; r < 4; r++) {
            const int ml = wm * 64 + mt * 16 + quad * 4 + r;
            float a = acc[mt][nt][r] + bias;
            float p = __shfl_xor(a, 1, 64);  // partner at d^1 (incl. its bias)
            float th = (float)((s0 + ml) & (SEQ - 1)) * invf;
            float sn, cs;
            __sincosf(th, &sn, &cs);  // inline v_sin/v_cos: NO libcall, NO scratch spill
            float res = (n & 1) ? fmaf(p, sn, a * cs) : fmaf(-p, sn, a * cs);
            CS[ml * 132 + nl] = (bf16)res;
          }
        }
      }
      __syncthreads();
      // coalesced store: 256 rows (2 heads x 128 s), 128 B each
      bf16* Odst = (z == 0) ? Oq : Ok;
#pragma unroll
      for (int g = 0; g < 8; g++) {
        int unit = g * 256 + tid;
        int chunk = unit & 7;          // 16B chunk within row
        int row = unit >> 3;           // 0..255
        int hl = row >> 7, sl = row & 127;
        bf16x8 v = *(const bf16x8*)(CS + sl * 132 + hl * 64 + chunk * 8);
        int hg = (tile_n >> 6) + hl;
        size_t o = ((size_t)(b * NH + hg) * SEQ + s0 + sl) * HD + chunk * 8;
        *(bf16x8*)(Odst + o) = v;
      }
    } else {
      // V^T: stage CS[n][m] (r-contiguous writes), rows = d, cols = s
#pragma unroll
      for (int nt = 0; nt < 4; nt++) {
        const int nl = wn * 64 + nt * 16 + l15;
        const float bias = Bsel[tile_n + nl];
#pragma unroll
        for (int mt = 0; mt < 4; mt++) {
          const int mb = wm * 64 + mt * 16 + quad * 4;
#pragma unroll
          for (int r = 0; r < 4; r++)
            CS[nl * 132 + mb + r] = (bf16)(acc[mt][nt][r] + bias);
        }
      }
      __syncthreads();
      // coalesced store: 128 rows (d), 256 B each
#pragma unroll
      for (int g = 0; g < 8; g++) {
        int unit = g * 256 + tid;
        int chunk = unit & 15;         // 16B chunk within row
        int row = unit >> 4;           // 0..127 (n_local)
        bf16x8 v = *(const bf16x8*)(CS + row * 132 + chunk * 8);
        int nglob = tile_n + row;
        int d = nglob & 63, hg = nglob >> 6;
        size_t o = ((size_t)(b * NH + hg) * HD + d) * SEQ + s0 + chunk * 8;
        *(bf16x8*)(Ovt + o) = v;
      }
    }
  } else {
    // out projection: f32 stores, 64B contiguous per quad-row
#pragma unroll
    for (int nt = 0; nt < 4; nt++) {
      const int n = tile_n + wn * 64 + nt * 16 + l15;
      const float bias = Bsel[n];
#pragma unroll
      for (int mt = 0; mt < 4; mt++) {
#pragma unroll
        for (int r = 0; r < 4; r++) {
          const int m = tile_m + wm * 64 + mt * 16 + quad * 4 + r;
          Oplain[(size_t)m * EMB + n] = acc[mt][nt][r] + bias;
        }
      }
    }
  }
}

// Flash attention v4: q-partitioned (v2 geometry: zero conflicts measured),
// but 128 q-rows/block — each wave owns TWO 16-row subtiles, so K/V fragment
// reads are amortized over 2x the MFMAs (40 b128 + 64 b16w per 64 MFMAs vs
// v2's 36+32 per 32). No cross-wave reduction (each wave owns its q rows).
// Fixed-max softmax (|s|<~4 << 88: exp2 can't overflow; shift-invariance ->
// m=0 exact); row sums deferred to one butterfly after the k-loop.
// LDS = 64 KB -> 2 blocks/CU; 512 blocks = exactly 2/CU.
__global__ __launch_bounds__(256) void flash_kernel(
    const bf16* __restrict__ Q,   // [bh][s][d]
    const bf16* __restrict__ Kk,  // [bh][s][d]
    const bf16* __restrict__ Vt,  // [bh][d][s]
    bf16* __restrict__ O)         // [b*S + s][h*64 + d]
{
  const int bh = blockIdx.y;
  const int qt = blockIdx.x;            // 128-row q tile
  const int tid = threadIdx.x, lane = tid & 63, w = tid >> 6;
  const int quad = lane >> 4, l15 = lane & 15;

  __shared__ __align__(16) unsigned char smem[65536];
  bf16* Ks = (bf16*)smem;             // 16 KB [128 krow][64 d], chunk^(row&7)
  bf16* Vs = (bf16*)(smem + 16384);   // 16 KB [64 d][128 s], chunk^(d&15)
  bf16* Ps = (bf16*)(smem + 32768);   // 32 KB [wave][32 q][128 k], chunk^(q&15)

  const bf16* qbase = Q  + (size_t)bh * SEQ * HD;
  const bf16* kbase = Kk + (size_t)bh * SEQ * HD;
  const bf16* vbase = Vt + (size_t)bh * HD * SEQ;

  // preload this wave's 32 q rows: subtile m rows = qt*128 + w*32 + m*16 + l15
  bf16x8 qf[2][2];
#pragma unroll
  for (int m = 0; m < 2; m++)
#pragma unroll
    for (int t = 0; t < 2; t++)
      qf[m][t] = *(const bf16x8*)(qbase + (size_t)(qt * 128 + w * 32 + m * 16 + l15) * HD
                                  + t * 32 + quad * 8);

  float lsum[2][4];
  f32x4 oacc[2][4];
#pragma unroll
  for (int m = 0; m < 2; m++)
#pragma unroll
    for (int i = 0; i < 4; i++) { lsum[m][i] = 0.f; oacc[m][i] = f32x4{0.f, 0.f, 0.f, 0.f}; }

  const float SCL = 0.1803368801111244f;  // log2(e)/8  (QK scale folded into exp2)

  for (int kt = 0; kt < SEQ / 128; kt++) {
    // stage K tile (16KB) and V^T tile (16KB) — v2 pattern (0 conflicts)
#pragma unroll
    for (int i = 0; i < 4; i++) {
      int r = w * 32 + i * 8 + (lane >> 3);             // K row 0..127
      int c = (lane & 7) ^ (r & 7);
      gl_lds16(kbase + (size_t)(kt * 128 + r) * HD + c * 8, Ks + (w * 32 + i * 8) * 64);
      int dv = w * 16 + i * 4 + (lane >> 4);            // V^T row (d) 0..63
      int cv = (lane & 15) ^ (dv & 15);
      gl_lds16(vbase + (size_t)dv * SEQ + kt * 128 + cv * 8, Vs + (w * 16 + i * 4) * 128);
    }
    __syncthreads();

    // S = Q K^T ; P = 2^(S*log2e/8): K frags loaded once, reused by both m
#pragma unroll
    for (int nt = 0; nt < 8; nt++) {
      int krow = nt * 16 + l15;                          // B-frag: n = lane&15
      bf16x8 kf[2];
#pragma unroll
      for (int t = 0; t < 2; t++)
        kf[t] = *(const bf16x8*)(Ks + krow * 64 + (((t * 4 + quad) ^ (krow & 7)) & 7) * 8);
#pragma unroll
      for (int m = 0; m < 2; m++) {
        f32x4 s = f32x4{0.f, 0.f, 0.f, 0.f};
        s = mfma16(qf[m][0], kf[0], s);
        s = mfma16(qf[m][1], kf[1], s);
#pragma unroll
        for (int r = 0; r < 4; r++) {
          float p = __builtin_amdgcn_exp2f(s[r] * SCL);
          lsum[m][r] += p;
          int row = m * 16 + quad * 4 + r;               // q-local 0..31
          int col = nt * 16 + l15;
          Ps[w * 4096 + row * 128 + (((col >> 3) ^ row) & 15) * 8 + (col & 7)] = (bf16)p;
        }
      }
    }

    // O += P V: V frags loaded once per t2, reused by both m
#pragma unroll
    for (int t2 = 0; t2 < 4; t2++) {
      bf16x8 vf[4];
#pragma unroll
      for (int dt = 0; dt < 4; dt++) {
        int d = dt * 16 + l15;
        vf[dt] = *(const bf16x8*)(Vs + d * 128 + (((t2 * 4 + quad) ^ (d & 15)) & 15) * 8);
      }
#pragma unroll
      for (int m = 0; m < 2; m++) {
        int row = m * 16 + l15;                          // A-frag: m-row = lane&15
        bf16x8 pf = *(const bf16x8*)(Ps + w * 4096 + row * 128
                                     + (((t2 * 4 + quad) ^ l15) & 15) * 8);
#pragma unroll
        for (int dt = 0; dt < 4; dt++)
          oacc[m][dt] = mfma16(pf, vf[dt], oacc[m][dt]);
      }
    }
    __syncthreads();
  }

  // row sums: one butterfly over l15 bits (rows live per-quad)
#pragma unroll
  for (int m = 0; m < 2; m++)
#pragma unroll
    for (int r = 0; r < 4; r++) {
      float s = lsum[m][r];
      s += __shfl_xor(s, 1, 64);
      s += __shfl_xor(s, 2, 64);
      s += __shfl_xor(s, 4, 64);
      s += __shfl_xor(s, 8, 64);
      lsum[m][r] = __builtin_amdgcn_rcpf(s);
    }

  const int b = bh >> 4, h = bh & 15;
#pragma unroll
  for (int m = 0; m < 2; m++)
#pragma unroll
    for (int dt = 0; dt < 4; dt++)
#pragma unroll
      for (int r = 0; r < 4; r++) {
        int srow = qt * 128 + w * 32 + m * 16 + quad * 4 + r;
        int dg = dt * 16 + l15;
        float val = oacc[m][dt][r] * lsum[m][r];
        O[((size_t)(b * SEQ + srow)) * EMB + h * HD + dg] = (bf16)val;
      }
}

extern "C" void kernel_launch(void* const* d_in, const int* in_sizes, int n_in,
                              void* d_out, int out_size, void* d_ws, size_t ws_size,
                              hipStream_t stream) {
  const float* x  = (const float*)d_in[0];
  const float* Wq = (const float*)d_in[1];
  const float* bq = (const float*)d_in[2];
  const float* Wk = (const float*)d_in[3];
  const float* bk = (const float*)d_in[4];
  const float* Wv = (const float*)d_in[5];
  const float* bv = (const float*)d_in[6];
  const float* Wo = (const float*)d_in[7];
  const float* bo = (const float*)d_in[8];

  const size_t XN = (size_t)MTOT * EMB;  // 4,194,304
  const size_t WN = (size_t)EMB * EMB;   // 1,048,576

  bf16* xb = (bf16*)d_ws;
  bf16* wq = xb + XN;                    // wq,wk,wv,wo contiguous (cvtw uses this)
  bf16* wk = wq + WN;
  bf16* wv = wk + WN;
  bf16* wo = wv + WN;
  bf16* q  = wo + WN;
  bf16* k  = q + XN;
  bf16* vt = k + XN;
  bf16* at = vt + XN;
  float* out = (float*)d_out;

  dim3 blk(256);
  cvt8_kernel<<<dim3((int)(XN / (256 * 8))), blk, 0, stream>>>(x, xb, (int)XN);
  cvtw_kernel<<<dim3((int)(WN / (256 * 8)), 4), blk, 0, stream>>>(Wq, Wk, Wv, Wo, wq);

  gemm_kernel<0><<<dim3(8, 32, 3), blk, 0, stream>>>(
      xb, wq, wk, wv, bq, bk, bv, q, k, vt, nullptr);
  flash_kernel<<<dim3(16, 32), blk, 0, stream>>>(q, k, vt, at);
  gemm_kernel<1><<<dim3(8, 32, 1), blk, 0, stream>>>(
      at, wo, nullptr, nullptr, bo, nullptr, nullptr, nullptr, nullptr, nullptr, out);
}